// Round 4
// baseline (132.417 us; speedup 1.0000x reference)
//
#include <hip/hip_runtime.h>
#include <math.h>

// Problem constants
#define T_TOTAL 131072
#define LB      512
#define NSTEPS  130561          // T - LB + 1
#define NPAD    130564          // NSTEPS rounded up to multiple of 4
#define OMF     0.99975f        // 1 - FEES
#define KC     -1.4426950408889634f   // -log2(e)

// ws layout (float offsets)
#define OFF_E    0
#define OFF_P0   (NPAD)
#define OFF_P    (2*NPAD)
#define OFF_BS   (2*NPAD + T_TOTAL)
#define OFF_BSS  (OFF_BS + 2048)
#define OFF_CP   (OFF_BSS + 2048)
#define OFF_CTR  (OFF_CP + 16)      // 64 uints (two barrier counters, padded)

static __device__ __forceinline__ float fast_rcp(float x) {
#if __has_builtin(__builtin_amdgcn_rcpf)
    return __builtin_amdgcn_rcpf(x);
#else
    return 1.0f / x;
#endif
}
static __device__ __forceinline__ float fast_rsq(float x) {
#if __has_builtin(__builtin_amdgcn_rsqf)
    return __builtin_amdgcn_rsqf(x);
#else
    return 1.0f / sqrtf(x);
#endif
}
static __device__ __forceinline__ float fast_exp2(float x) {
#if __has_builtin(__builtin_amdgcn_exp2f)
    return __builtin_amdgcn_exp2f(x);
#else
    return exp2f(x);
#endif
}

// Device-scope grid barrier (all NBLK blocks co-resident: 128 blocks on 256 CUs).
static __device__ __forceinline__ void grid_barrier(unsigned* ctr, unsigned nblk) {
    __syncthreads();
    if (threadIdx.x == 0) {
        __threadfence();  // release our global writes
        __hip_atomic_fetch_add(ctr, 1u, __ATOMIC_ACQ_REL, __HIP_MEMORY_SCOPE_AGENT);
        while (__hip_atomic_load(ctr, __ATOMIC_ACQUIRE, __HIP_MEMORY_SCOPE_AGENT) < nblk) {
            __builtin_amdgcn_s_sleep(8);
        }
        __threadfence();  // acquire: invalidate L1 before block reads others' data
    }
    __syncthreads();
}

// Zero the barrier counters (runs before fused kernel each call; no reliance on poison).
__global__ __launch_bounds__(64) void init_kernel(unsigned* ctr) {
    ctr[threadIdx.x] = 0u;
}

__global__ __launch_bounds__(256) void fused_kernel(
    const float* __restrict__ features,
    const float* __restrict__ asset_returns,
    const float* __restrict__ theta,
    const float* __restrict__ p_init,
    float* __restrict__ out,
    float* __restrict__ ws)
{
    float* e_out = ws + OFF_E;
    float* p0    = ws + OFF_P0;
    float* P     = ws + OFF_P;
    float* bs    = ws + OFF_BS;
    float* bss   = ws + OFF_BSS;
    float* cpool = ws + OFF_CP;
    unsigned* ctr = (unsigned*)(ws + OFF_CTR);

    __shared__ float f_lds[1536];
    __shared__ float th_lds[512];
    const int tid = threadIdx.x;
    const int b   = blockIdx.x;

    // ================= Phase A: FIR-tiled precompute =================
    {
        const int base = b * 1024;
        {
            const float4* fg = (const float4*)features;
            float4* f4s = (float4*)f_lds;
            int g0 = b * 256 + tid; g0 = g0 > 32767 ? 32767 : g0;
            f4s[tid] = fg[g0];
            if (tid < 128) {
                int g1 = b * 256 + 256 + tid; g1 = g1 > 32767 ? 32767 : g1;
                f4s[256 + tid] = fg[g1];
            }
            const float4* tg = (const float4*)theta;
            float4* t4s = (float4*)th_lds;
            if (tid >= 128 && tid < 256) t4s[tid - 128] = tg[tid - 128];
        }
        if (b == 0) {
            P[tid] = p_init[tid < 511 ? tid : 510];
            if (tid + 256 < 511) P[tid + 256] = p_init[tid + 256];
        }
        __syncthreads();

        // wave-level thsum (wave-uniform; removed from main loop)
        float thsum = 0.f;
        {
            int l6 = tid & 63;
#pragma unroll
            for (int j = 0; j < 8; ++j) thsum += th_lds[l6 + 64 * j];
#pragma unroll
            for (int d = 32; d; d >>= 1) thsum += __shfl_xor(thsum, d, 64);
        }

        const float4* f4 = (const float4*)f_lds;
        const float4* t4 = (const float4*)th_lds;

        float d0 = 0.f, d1 = 0.f, d2 = 0.f, d3 = 0.f;
        float fsum0 = 0.f, fss0 = 0.f;
        float4 a = f4[tid];
        const float a00 = a.x, a01 = a.y, a02 = a.z;
#pragma unroll 4
        for (int j = 0; j < 128; ++j) {
            float4 bb = f4[tid + j + 1];
            float4 th = t4[j];
            d0 = fmaf(th.x, a.x, d0); d0 = fmaf(th.y, a.y, d0);
            d0 = fmaf(th.z, a.z, d0); d0 = fmaf(th.w, a.w, d0);
            d1 = fmaf(th.x, a.y, d1); d1 = fmaf(th.y, a.z, d1);
            d1 = fmaf(th.z, a.w, d1); d1 = fmaf(th.w, bb.x, d1);
            d2 = fmaf(th.x, a.z, d2); d2 = fmaf(th.y, a.w, d2);
            d2 = fmaf(th.z, bb.x, d2); d2 = fmaf(th.w, bb.y, d2);
            d3 = fmaf(th.x, a.w, d3); d3 = fmaf(th.y, bb.x, d3);
            d3 = fmaf(th.z, bb.y, d3); d3 = fmaf(th.w, bb.z, d3);
            fsum0 += (a.x + a.y) + (a.z + a.w);
            fss0 = fmaf(a.x, a.x, fss0); fss0 = fmaf(a.y, a.y, fss0);
            fss0 = fmaf(a.z, a.z, fss0); fss0 = fmaf(a.w, a.w, fss0);
            a = bb;
        }
        const float b00 = a.x, b01 = a.y, b02 = a.z;
        const float fsum1 = fsum0 - a00 + b00;
        const float fsum2 = fsum1 - a01 + b01;
        const float fsum3 = fsum2 - a02 + b02;
        float fss1 = fss0 - a00 * a00; fss1 = fmaf(b00, b00, fss1);
        float fss2 = fss1 - a01 * a01; fss2 = fmaf(b01, b01, fss2);
        float fss3 = fss2 - a02 * a02; fss3 = fmaf(b02, b02, fss3);

        const float th512 = theta[512];
        const float th513 = theta[513];
        const float sall  = thsum + th512 + th513;
        const float A_    = (512.0f - 1.0f / 514.0f) / 513.0f;
        const float rsqA  = fast_rsq(A_);
        const float cE    = th513 - sall * (1.0f / 514.0f);
        if (b == 0 && tid == 0) cpool[0] = KC * (th512 - sall * (1.0f / 514.0f));  // Gp

        float ez[4], pv[4];
        const float fs_[4] = { fsum0, fsum1, fsum2, fsum3 };
        const float fq_[4] = { fss0,  fss1,  fss2,  fss3  };
        const float dd_[4] = { d0, d1, d2, d3 };
#pragma unroll
        for (int c = 0; c < 4; ++c) {
            float m    = fs_[c] * (1.0f / 512.0f);
            float varw = (fq_[c] - fs_[c] * m) * (1.0f / 511.0f);
            float dn   = (dd_[c] - m * thsum) * fast_rsq(varw);
            ez[c] = KC * (dn + cE);
            pv[c] = fast_rcp(1.0f + fast_exp2(ez[c] * rsqA));
        }

        const int t4i = base + 4 * tid;
        if (t4i + 3 < NSTEPS) {
            ((float4*)e_out)[b * 256 + tid] = make_float4(ez[0], ez[1], ez[2], ez[3]);
            ((float4*)p0)[b * 256 + tid]    = make_float4(pv[0], pv[1], pv[2], pv[3]);
        } else {
#pragma unroll
            for (int c = 0; c < 4; ++c)
                if (t4i + c < NSTEPS) { e_out[t4i + c] = ez[c]; p0[t4i + c] = pv[c]; }
        }

        // per-64-step partials: 16 threads cover one 64-chunk
        float c1 = 0.f, c2 = 0.f;
#pragma unroll
        for (int c = 0; c < 4; ++c) {
            float p = (t4i + c < NSTEPS) ? pv[c] : 0.f;
            c1 += p; c2 = fmaf(p, p, c2);
        }
#pragma unroll
        for (int d = 8; d; d >>= 1) {
            c1 += __shfl_down(c1, d, 16);
            c2 += __shfl_down(c2, d, 16);
        }
        if ((tid & 15) == 0) {
            int idx = b * 16 + (tid >> 4);   // 0..2047
            bs[idx] = c1; bss[idx] = c2;
        }
    }

    // ================= barrier 1 =================
    grid_barrier(&ctr[0], 128);

    // ================= Phase B: 2048 chunks x (8 warm + 64) p-recurrence =================
    if (b < 32 && tid < 64) {
        const int l = tid;
        const int g = b * 64 + l;            // 0..2047

        // exact p_init sums
        float sa = 0.f, qa = 0.f;
        for (int j = l; j < 511; j += 64) { float v = p_init[j]; sa += v; qa = fmaf(v, v, qa); }
#pragma unroll
        for (int d = 32; d; d >>= 1) { sa += __shfl_xor(sa, d, 64); qa += __shfl_xor(qa, d, 64); }

        // sum of partials over previous blocks
        float ba = 0.f, ca = 0.f;
        for (int j = l; j < b * 64; j += 64) { ba += bs[j]; ca += bss[j]; }
#pragma unroll
        for (int d = 32; d; d >>= 1) { ba += __shfl_xor(ba, d, 64); ca += __shfl_xor(ca, d, 64); }

        // in-block exclusive scan of this block's 64 partials
        float vb = bs[g], vc = bss[g];
        float ib = vb, ic = vc;
#pragma unroll
        for (int d = 1; d < 64; d <<= 1) {
            float ub = __shfl_up(ib, d, 64);
            float uc = __shfl_up(ic, d, 64);
            if (l >= d) { ib += ub; ic += uc; }
        }
        float s  = sa + ba + (ib - vb);
        float ss = qa + ca + (ic - vc);

        if (g <= 2040) {
            const float Gp = cpool[0];
            const float A_ = (512.0f - 1.0f / 514.0f) / 513.0f;
            const float B_ = (1.0f - 1.0f / 514.0f) / 513.0f;
            const float C_ = -2.0f / (514.0f * 513.0f);

            const int k0   = g * 64;
            const int kend = (k0 + 64 < NSTEPS) ? k0 + 64 : NSTEPS;
            const int kw   = (g == 0) ? 0 : k0 - 8;

            float plast = (g == 0) ? p_init[510] : p0[k0 - 9];
            float nf    = 511.0f + (float)k0;
            float rnm1  = fast_rcp(nf - 1.0f);
            const float mean_f = s * fast_rcp(nf);
            const float rv_f   = fast_rsq(fmaf(-s, mean_f, ss) * rnm1);

            const float4* e4 = (const float4*)(e_out + kw);   // kw % 4 == 0
            const int maxi = (NPAD / 4 - 1) - (kw >> 2);

            float4 er[18];
#pragma unroll
            for (int i = 0; i < 18; ++i) er[i] = e4[i < maxi ? i : maxi];

#define BSTEP(EK, I) { \
    float rn   = fast_rcp(nf); \
    float mean = s * rn; \
    float varp = fmaf(-s, mean, ss) * rnm1; \
    float rv   = fast_rsq(varp); \
    float u    = (plast - mean) * rv; \
    float vx   = fmaf(u, fmaf(B_, u, C_), A_); \
    float r2   = fast_rsq(vx); \
    float z    = fmaf(u, Gp, (EK)) * r2; \
    float w    = fast_exp2(z); \
    float pnew = fast_rcp(1.0f + w); \
    s += pnew; ss = fmaf(pnew, pnew, ss); plast = pnew; \
    rnm1 = rn; nf += 1.0f; \
    int k = kw + (I); \
    if (k < kend) P[511 + k] = pnew; }
#define BWARM(EK) { \
    float u  = (plast - mean_f) * rv_f; \
    float vx = fmaf(u, fmaf(B_, u, C_), A_); \
    float r2 = fast_rsq(vx); \
    float z  = fmaf(u, Gp, (EK)) * r2; \
    plast = fast_rcp(1.0f + fast_exp2(z)); }
#define B4(Q, IB) { BSTEP(Q.x, IB+0); BSTEP(Q.y, IB+1); BSTEP(Q.z, IB+2); BSTEP(Q.w, IB+3); }
#define W4(Q) { BWARM(Q.x); BWARM(Q.y); BWARM(Q.z); BWARM(Q.w); }

            if (g == 0) { B4(er[0], 0); B4(er[1], 4); }
            else        { W4(er[0]);    W4(er[1]);    }
            B4(er[2],  8);  B4(er[3], 12);  B4(er[4], 16);  B4(er[5], 20);
            B4(er[6], 24);  B4(er[7], 28);  B4(er[8], 32);  B4(er[9], 36);
            B4(er[10],40);  B4(er[11],44);  B4(er[12],48);  B4(er[13],52);
            B4(er[14],56);  B4(er[15],60);  B4(er[16],64);  B4(er[17],68);
#undef BSTEP
#undef BWARM
#undef B4
#undef W4
        }
    }

    // ================= barrier 2 =================
    grid_barrier(&ctr[32], 128);

    // ================= Phase C: 4096 chunks x (8 warm + 32) portfolio =================
    if (tid < 32) {
        const int g = b * 32 + tid;          // 0..4095
        const int t0   = g * 32;
        const int t0w  = (g == 0) ? 1 : t0;
        const int tend = (t0 + 32 < T_TOTAL) ? t0 + 32 : T_TOTAL;
        const int tw   = (g == 0) ? 0 : t0 - 8;

        float x = P[(g == 0) ? 0 : (tw - 1)];
        float inv = x, cash = 1.0f - x, pvprev = 1.0f;
        if (g == 0) out[0] = 1.0f;

        const float4* P4 = (const float4*)(P + tw);             // tw % 4 == 0
        const float4* A4 = (const float4*)(asset_returns + tw);

        float4 pr[10], ar[10];
#pragma unroll
        for (int i = 0; i < 10; ++i) { pr[i] = P4[i]; ar[i] = A4[i]; }

#define CST(RR, PPV, I) { \
    int t = tw + (I); \
    if (t >= 1) { \
        float invn  = inv * (RR); \
        float pv    = invn + cash; \
        float delta = fmaf(pv, (PPV), -invn); \
        float dfee  = delta * OMF; \
        bool  pos   = delta > 0.0f; \
        inv  = invn + (pos ? dfee : delta); \
        cash = cash - (pos ? delta : dfee); \
        float pvn = inv + cash; \
        if (t >= t0w && t < tend) out[t] = pvn * fast_rcp(pvprev); \
        pvprev = pvn; } }
#define C4(PQ, AQ, IB) { CST(AQ.x, PQ.x, IB+0); CST(AQ.y, PQ.y, IB+1); \
                         CST(AQ.z, PQ.z, IB+2); CST(AQ.w, PQ.w, IB+3); }

        C4(pr[0], ar[0], 0);   C4(pr[1], ar[1], 4);
        C4(pr[2], ar[2], 8);   C4(pr[3], ar[3], 12);
        C4(pr[4], ar[4], 16);  C4(pr[5], ar[5], 20);
        C4(pr[6], ar[6], 24);  C4(pr[7], ar[7], 28);
        C4(pr[8], ar[8], 32);  C4(pr[9], ar[9], 36);
#undef CST
#undef C4
    }
}

extern "C" void kernel_launch(void* const* d_in, const int* in_sizes, int n_in,
                              void* d_out, int out_size, void* d_ws, size_t ws_size,
                              hipStream_t stream) {
    const float* features      = (const float*)d_in[0];
    const float* asset_returns = (const float*)d_in[1];
    const float* theta         = (const float*)d_in[2];
    const float* p_init        = (const float*)d_in[3];
    float* out = (float*)d_out;
    float* ws  = (float*)d_ws;
    unsigned* ctr = (unsigned*)(ws + OFF_CTR);

    init_kernel<<<1, 64, 0, stream>>>(ctr);
    fused_kernel<<<128, 256, 0, stream>>>(features, asset_returns, theta, p_init, out, ws);
}

// Round 5
// 96.459 us; speedup vs baseline: 1.3728x; 1.3728x over previous
//
#include <hip/hip_runtime.h>
#include <math.h>

// Problem constants
#define T_TOTAL 131072
#define LB      512
#define NSTEPS  130561          // T - LB + 1
#define NPAD    130564          // NSTEPS rounded up to multiple of 4
#define OMF     0.99975f        // 1 - FEES
#define KC     -1.4426950408889634f   // -log2(e)

// ws layout (float offsets)
#define OFF_E    0
#define OFF_P0   (NPAD)
#define OFF_P    (2*NPAD)
#define OFF_BS   (2*NPAD + T_TOTAL)
#define OFF_BSS  (OFF_BS + 2048)
#define OFF_CP   (OFF_BSS + 2048)

static __device__ __forceinline__ float fast_rcp(float x) {
#if __has_builtin(__builtin_amdgcn_rcpf)
    return __builtin_amdgcn_rcpf(x);
#else
    return 1.0f / x;
#endif
}
static __device__ __forceinline__ float fast_rsq(float x) {
#if __has_builtin(__builtin_amdgcn_rsqf)
    return __builtin_amdgcn_rsqf(x);
#else
    return 1.0f / sqrtf(x);
#endif
}
static __device__ __forceinline__ float fast_exp2(float x) {
#if __has_builtin(__builtin_amdgcn_exp2f)
    return __builtin_amdgcn_exp2f(x);
#else
    return exp2f(x);
#endif
}

// -------- Phase A: FIR-tiled precompute (4 outputs/thread) --------
// 128 blocks x 256 threads; block covers 1024 t's.
// Emits e[t], p0[t], per-64-chunk partials bs/bss (2048 entries),
// copies p_init -> P[0..510], writes Gp to cpool[0].
__global__ __launch_bounds__(256, 1) void precompute_kernel(
    const float* __restrict__ features,
    const float* __restrict__ theta,
    const float* __restrict__ p_init,
    float* __restrict__ e_out,
    float* __restrict__ p0_out,
    float* __restrict__ P,
    float* __restrict__ bs,
    float* __restrict__ bss,
    float* __restrict__ cpool)
{
    __shared__ float f_lds[1536];
    __shared__ float th_lds[512];
    const int tid = threadIdx.x;
    const int b   = blockIdx.x;
    const int base = b * 1024;

    {
        const float4* fg = (const float4*)features;
        float4* f4s = (float4*)f_lds;
        int g0 = b * 256 + tid; g0 = g0 > 32767 ? 32767 : g0;
        f4s[tid] = fg[g0];
        if (tid < 128) {
            int g1 = b * 256 + 256 + tid; g1 = g1 > 32767 ? 32767 : g1;
            f4s[256 + tid] = fg[g1];
        }
        const float4* tg = (const float4*)theta;
        float4* t4s = (float4*)th_lds;
        if (tid >= 128 && tid < 256) t4s[tid - 128] = tg[tid - 128];
    }
    if (b == 0) {
        P[tid] = p_init[tid < 511 ? tid : 510];
        if (tid + 256 < 511) P[tid + 256] = p_init[tid + 256];
    }
    __syncthreads();

    // wave-level thsum (wave-uniform)
    float thsum = 0.f;
    {
        int l6 = tid & 63;
#pragma unroll
        for (int j = 0; j < 8; ++j) thsum += th_lds[l6 + 64 * j];
#pragma unroll
        for (int d = 32; d; d >>= 1) thsum += __shfl_xor(thsum, d, 64);
    }

    const float4* f4 = (const float4*)f_lds;
    const float4* t4 = (const float4*)th_lds;

    float d0 = 0.f, d1 = 0.f, d2 = 0.f, d3 = 0.f;
    float fsum0 = 0.f, fss0 = 0.f;
    float4 a = f4[tid];
    const float a00 = a.x, a01 = a.y, a02 = a.z;
#pragma unroll 4
    for (int j = 0; j < 128; ++j) {
        float4 bb = f4[tid + j + 1];
        float4 th = t4[j];
        d0 = fmaf(th.x, a.x, d0); d0 = fmaf(th.y, a.y, d0);
        d0 = fmaf(th.z, a.z, d0); d0 = fmaf(th.w, a.w, d0);
        d1 = fmaf(th.x, a.y, d1); d1 = fmaf(th.y, a.z, d1);
        d1 = fmaf(th.z, a.w, d1); d1 = fmaf(th.w, bb.x, d1);
        d2 = fmaf(th.x, a.z, d2); d2 = fmaf(th.y, a.w, d2);
        d2 = fmaf(th.z, bb.x, d2); d2 = fmaf(th.w, bb.y, d2);
        d3 = fmaf(th.x, a.w, d3); d3 = fmaf(th.y, bb.x, d3);
        d3 = fmaf(th.z, bb.y, d3); d3 = fmaf(th.w, bb.z, d3);
        fsum0 += (a.x + a.y) + (a.z + a.w);
        fss0 = fmaf(a.x, a.x, fss0); fss0 = fmaf(a.y, a.y, fss0);
        fss0 = fmaf(a.z, a.z, fss0); fss0 = fmaf(a.w, a.w, fss0);
        a = bb;
    }
    const float b00 = a.x, b01 = a.y, b02 = a.z;
    const float fsum1 = fsum0 - a00 + b00;
    const float fsum2 = fsum1 - a01 + b01;
    const float fsum3 = fsum2 - a02 + b02;
    float fss1 = fss0 - a00 * a00; fss1 = fmaf(b00, b00, fss1);
    float fss2 = fss1 - a01 * a01; fss2 = fmaf(b01, b01, fss2);
    float fss3 = fss2 - a02 * a02; fss3 = fmaf(b02, b02, fss3);

    const float th512 = theta[512];
    const float th513 = theta[513];
    const float sall  = thsum + th512 + th513;
    const float A_    = (512.0f - 1.0f / 514.0f) / 513.0f;
    const float rsqA  = fast_rsq(A_);
    const float cE    = th513 - sall * (1.0f / 514.0f);
    if (b == 0 && tid == 0) cpool[0] = KC * (th512 - sall * (1.0f / 514.0f));  // Gp

    float ez[4], pv[4];
    const float fs_[4] = { fsum0, fsum1, fsum2, fsum3 };
    const float fq_[4] = { fss0,  fss1,  fss2,  fss3  };
    const float dd_[4] = { d0, d1, d2, d3 };
#pragma unroll
    for (int c = 0; c < 4; ++c) {
        float m    = fs_[c] * (1.0f / 512.0f);
        float varw = (fq_[c] - fs_[c] * m) * (1.0f / 511.0f);
        float dn   = (dd_[c] - m * thsum) * fast_rsq(varw);
        ez[c] = KC * (dn + cE);
        pv[c] = fast_rcp(1.0f + fast_exp2(ez[c] * rsqA));
    }

    const int t4i = base + 4 * tid;
    if (t4i + 3 < NSTEPS) {
        ((float4*)e_out)[b * 256 + tid]  = make_float4(ez[0], ez[1], ez[2], ez[3]);
        ((float4*)p0_out)[b * 256 + tid] = make_float4(pv[0], pv[1], pv[2], pv[3]);
    } else {
#pragma unroll
        for (int c = 0; c < 4; ++c)
            if (t4i + c < NSTEPS) { e_out[t4i + c] = ez[c]; p0_out[t4i + c] = pv[c]; }
    }

    // per-64-step partials: 16 threads cover one 64-chunk
    float c1 = 0.f, c2 = 0.f;
#pragma unroll
    for (int c = 0; c < 4; ++c) {
        float p = (t4i + c < NSTEPS) ? pv[c] : 0.f;
        c1 += p; c2 = fmaf(p, p, c2);
    }
#pragma unroll
    for (int d = 8; d; d >>= 1) {
        c1 += __shfl_down(c1, d, 16);
        c2 += __shfl_down(c2, d, 16);
    }
    if ((tid & 15) == 0) {
        int idx = b * 16 + (tid >> 4);   // 0..2047
        bs[idx] = c1; bss[idx] = c2;
    }
}

// -------- Phase B: 2048 chunks x (12 warm + 64) p-recurrence --------
// 32 blocks x 64 lanes; one chunk per lane. (64,1): full VGPR budget, no spills.
__global__ __launch_bounds__(64, 1) void pos_kernel(
    const float* __restrict__ p_init,
    const float* __restrict__ e,
    const float* __restrict__ p0,
    const float* __restrict__ bs,
    const float* __restrict__ bss,
    const float* __restrict__ cpool,
    float* __restrict__ P)
{
    const int l = threadIdx.x;
    const int b = blockIdx.x;
    const int g = b * 64 + l;            // 0..2047

    // exact p_init sums
    float sa = 0.f, qa = 0.f;
    for (int j = l; j < 511; j += 64) { float v = p_init[j]; sa += v; qa = fmaf(v, v, qa); }
#pragma unroll
    for (int d = 32; d; d >>= 1) { sa += __shfl_xor(sa, d, 64); qa += __shfl_xor(qa, d, 64); }

    // sum of partials over previous blocks
    float ba = 0.f, ca = 0.f;
    for (int j = l; j < b * 64; j += 64) { ba += bs[j]; ca += bss[j]; }
#pragma unroll
    for (int d = 32; d; d >>= 1) { ba += __shfl_xor(ba, d, 64); ca += __shfl_xor(ca, d, 64); }

    // in-block exclusive scan of this block's 64 partials
    float vb = bs[g], vc = bss[g];
    float ib = vb, ic = vc;
#pragma unroll
    for (int d = 1; d < 64; d <<= 1) {
        float ub = __shfl_up(ib, d, 64);
        float uc = __shfl_up(ic, d, 64);
        if (l >= d) { ib += ub; ic += uc; }
    }
    float s  = sa + ba + (ib - vb);
    float ss = qa + ca + (ic - vc);

    if (g > 2040) return;   // last useful chunk: k0 = 2040*64 = 130560 < NSTEPS

    const float Gp = cpool[0];
    const float A_ = (512.0f - 1.0f / 514.0f) / 513.0f;
    const float B_ = (1.0f - 1.0f / 514.0f) / 513.0f;
    const float C_ = -2.0f / (514.0f * 513.0f);

    const int k0   = g * 64;
    const int kend = (k0 + 64 < NSTEPS) ? k0 + 64 : NSTEPS;
    const int kw   = (g == 0) ? 0 : k0 - 12;

    float plast = (g == 0) ? p_init[510] : p0[k0 - 13];
    float nf    = 511.0f + (float)k0;
    float rnm1  = fast_rcp(nf - 1.0f);
    const float mean_f = s * fast_rcp(nf);
    const float rv_f   = fast_rsq(fmaf(-s, mean_f, ss) * rnm1);

    const float4* e4 = (const float4*)(e + kw);   // kw % 4 == 0
    const int maxi = (NPAD / 4 - 1) - (kw >> 2);

    float4 er[19];
#pragma unroll
    for (int i = 0; i < 19; ++i) er[i] = e4[i < maxi ? i : maxi];

#define BSTEP(EK, I) { \
    float rn   = fast_rcp(nf); \
    float mean = s * rn; \
    float varp = fmaf(-s, mean, ss) * rnm1; \
    float rv   = fast_rsq(varp); \
    float u    = (plast - mean) * rv; \
    float vx   = fmaf(u, fmaf(B_, u, C_), A_); \
    float r2   = fast_rsq(vx); \
    float z    = fmaf(u, Gp, (EK)) * r2; \
    float w    = fast_exp2(z); \
    float pnew = fast_rcp(1.0f + w); \
    s += pnew; ss = fmaf(pnew, pnew, ss); plast = pnew; \
    rnm1 = rn; nf += 1.0f; \
    int k = kw + (I); \
    if (k < kend) P[511 + k] = pnew; }
#define BWARM(EK) { \
    float u  = (plast - mean_f) * rv_f; \
    float vx = fmaf(u, fmaf(B_, u, C_), A_); \
    float r2 = fast_rsq(vx); \
    float z  = fmaf(u, Gp, (EK)) * r2; \
    plast = fast_rcp(1.0f + fast_exp2(z)); }
#define B4(Q, IB) { BSTEP(Q.x, IB+0); BSTEP(Q.y, IB+1); BSTEP(Q.z, IB+2); BSTEP(Q.w, IB+3); }
#define W4(Q) { BWARM(Q.x); BWARM(Q.y); BWARM(Q.z); BWARM(Q.w); }

    if (g == 0) { B4(er[0], 0); B4(er[1], 4); B4(er[2], 8); }
    else        { W4(er[0]);    W4(er[1]);    W4(er[2]);    }
    B4(er[3], 12);  B4(er[4], 16);  B4(er[5], 20);  B4(er[6], 24);
    B4(er[7], 28);  B4(er[8], 32);  B4(er[9], 36);  B4(er[10],40);
    B4(er[11],44);  B4(er[12],48);  B4(er[13],52);  B4(er[14],56);
    B4(er[15],60);  B4(er[16],64);  B4(er[17],68);  B4(er[18],72);
#undef BSTEP
#undef BWARM
#undef B4
#undef W4
}

// -------- Phase C: 4096 chunks x (8 warm + 32) portfolio --------
// 64 blocks x 64 lanes; one chunk per lane.
__global__ __launch_bounds__(64, 1) void port_kernel(
    const float* __restrict__ ar,
    const float* __restrict__ Pp,
    float* __restrict__ out)
{
    const int g = blockIdx.x * 64 + threadIdx.x;   // 0..4095
    const int t0   = g * 32;
    const int t0w  = (g == 0) ? 1 : t0;
    const int tend = (t0 + 32 < T_TOTAL) ? t0 + 32 : T_TOTAL;
    const int tw   = (g == 0) ? 0 : t0 - 8;

    float x = Pp[(g == 0) ? 0 : (tw - 1)];
    float inv = x, cash = 1.0f - x, pvprev = 1.0f;
    if (g == 0) out[0] = 1.0f;

    const float4* P4 = (const float4*)(Pp + tw);   // tw % 4 == 0
    const float4* A4 = (const float4*)(ar + tw);

    float4 pr[10], arr[10];
#pragma unroll
    for (int i = 0; i < 10; ++i) { pr[i] = P4[i]; arr[i] = A4[i]; }

#define CST(RR, PPV, I) { \
    int t = tw + (I); \
    if (t >= 1) { \
        float invn  = inv * (RR); \
        float pv    = invn + cash; \
        float delta = fmaf(pv, (PPV), -invn); \
        float dfee  = delta * OMF; \
        bool  pos   = delta > 0.0f; \
        inv  = invn + (pos ? dfee : delta); \
        cash = cash - (pos ? delta : dfee); \
        float pvn = inv + cash; \
        if (t >= t0w && t < tend) out[t] = pvn * fast_rcp(pvprev); \
        pvprev = pvn; } }
#define C4(PQ, AQ, IB) { CST(AQ.x, PQ.x, IB+0); CST(AQ.y, PQ.y, IB+1); \
                         CST(AQ.z, PQ.z, IB+2); CST(AQ.w, PQ.w, IB+3); }

    C4(pr[0], arr[0], 0);   C4(pr[1], arr[1], 4);
    C4(pr[2], arr[2], 8);   C4(pr[3], arr[3], 12);
    C4(pr[4], arr[4], 16);  C4(pr[5], arr[5], 20);
    C4(pr[6], arr[6], 24);  C4(pr[7], arr[7], 28);
    C4(pr[8], arr[8], 32);  C4(pr[9], arr[9], 36);
#undef CST
#undef C4
}

extern "C" void kernel_launch(void* const* d_in, const int* in_sizes, int n_in,
                              void* d_out, int out_size, void* d_ws, size_t ws_size,
                              hipStream_t stream) {
    const float* features      = (const float*)d_in[0];
    const float* asset_returns = (const float*)d_in[1];
    const float* theta         = (const float*)d_in[2];
    const float* p_init        = (const float*)d_in[3];
    float* out = (float*)d_out;
    float* ws  = (float*)d_ws;

    float* e_arr = ws + OFF_E;
    float* p0    = ws + OFF_P0;
    float* P     = ws + OFF_P;
    float* bs    = ws + OFF_BS;
    float* bss   = ws + OFF_BSS;
    float* cpool = ws + OFF_CP;

    precompute_kernel<<<128, 256, 0, stream>>>(features, theta, p_init,
                                               e_arr, p0, P, bs, bss, cpool);
    pos_kernel<<<32, 64, 0, stream>>>(p_init, e_arr, p0, bs, bss, cpool, P);
    port_kernel<<<64, 64, 0, stream>>>(asset_returns, P, out);
}

// Round 6
// 84.775 us; speedup vs baseline: 1.5620x; 1.1378x over previous
//
#include <hip/hip_runtime.h>
#include <math.h>

// Problem constants
#define T_TOTAL 131072
#define LB      512
#define NSTEPS  130561          // T - LB + 1
#define NPAD    130564          // NSTEPS rounded up to multiple of 4
#define OMF     0.99975f        // 1 - FEES
#define KC     -1.4426950408889634f   // -log2(e)

// ws layout (float offsets)
#define OFF_E    0
#define OFF_P0   (NPAD)
#define OFF_P    (2*NPAD)
#define OFF_BS   (2*NPAD + T_TOTAL)
#define OFF_BSS  (OFF_BS + 2048)
#define OFF_CP   (OFF_BSS + 2048)

static __device__ __forceinline__ float fast_rcp(float x) {
#if __has_builtin(__builtin_amdgcn_rcpf)
    return __builtin_amdgcn_rcpf(x);
#else
    return 1.0f / x;
#endif
}
static __device__ __forceinline__ float fast_rsq(float x) {
#if __has_builtin(__builtin_amdgcn_rsqf)
    return __builtin_amdgcn_rsqf(x);
#else
    return 1.0f / sqrtf(x);
#endif
}
static __device__ __forceinline__ float fast_exp2(float x) {
#if __has_builtin(__builtin_amdgcn_exp2f)
    return __builtin_amdgcn_exp2f(x);
#else
    return exp2f(x);
#endif
}

// -------- Phase A: split-K FIR precompute --------
// 256 blocks x 256 threads. Block covers 512 outputs; threads tid&127 own an
// output quad, tid>>7 selects tap-half (256 taps each). Halves combined via LDS.
// Emits e[t], p0[t], per-64-chunk partials bs/bss (2048), P[0..510], Gp.
__global__ __launch_bounds__(256, 1) void precompute_kernel(
    const float* __restrict__ features,
    const float* __restrict__ theta,
    const float* __restrict__ p_init,
    float* __restrict__ e_out,
    float* __restrict__ p0_out,
    float* __restrict__ P,
    float* __restrict__ bs,
    float* __restrict__ bss,
    float* __restrict__ cpool)
{
    __shared__ float f_lds[1088];          // 272 float4
    __shared__ float th_lds[512];          // 128 float4
    __shared__ float part_lds[128][7];     // stride 7: conflict-free combine
    const int tid = threadIdx.x;
    const int b   = blockIdx.x;
    const int q   = tid & 127;             // output-quad index in block
    const int h   = tid >> 7;              // tap half (0/1)

    {
        const float4* fg = (const float4*)features;
        float4* f4s = (float4*)f_lds;
        int g0 = b * 128 + tid; g0 = g0 > 32767 ? 32767 : g0;
        f4s[tid] = fg[g0];
        if (tid < 16) {
            int g1 = b * 128 + 256 + tid; g1 = g1 > 32767 ? 32767 : g1;
            f4s[256 + tid] = fg[g1];
        }
        const float4* tg = (const float4*)theta;
        float4* t4s = (float4*)th_lds;
        if (h == 1) t4s[q] = tg[q];
    }
    if (b == 0) {
        P[tid] = p_init[tid < 511 ? tid : 510];
        if (tid + 256 < 511) P[tid + 256] = p_init[tid + 256];
    }
    __syncthreads();

    // wave-uniform thsum
    float thsum = 0.f;
    {
        int l6 = tid & 63;
#pragma unroll
        for (int j = 0; j < 8; ++j) thsum += th_lds[l6 + 64 * j];
#pragma unroll
        for (int d = 32; d; d >>= 1) thsum += __shfl_xor(thsum, d, 64);
    }

    const float4* f4 = (const float4*)f_lds;
    const float4* t4 = (const float4*)th_lds;

    float d0 = 0.f, d1 = 0.f, d2 = 0.f, d3 = 0.f;
    float fsum0 = 0.f, fss0 = 0.f;
    const int jt0 = 64 * h;
    float4 a = f4[q + jt0];
#pragma unroll 4
    for (int j = 0; j < 64; ++j) {
        float4 bb = f4[q + jt0 + j + 1];
        float4 th = t4[jt0 + j];
        d0 = fmaf(th.x, a.x, d0); d0 = fmaf(th.y, a.y, d0);
        d0 = fmaf(th.z, a.z, d0); d0 = fmaf(th.w, a.w, d0);
        d1 = fmaf(th.x, a.y, d1); d1 = fmaf(th.y, a.z, d1);
        d1 = fmaf(th.z, a.w, d1); d1 = fmaf(th.w, bb.x, d1);
        d2 = fmaf(th.x, a.z, d2); d2 = fmaf(th.y, a.w, d2);
        d2 = fmaf(th.z, bb.x, d2); d2 = fmaf(th.w, bb.y, d2);
        d3 = fmaf(th.x, a.w, d3); d3 = fmaf(th.y, bb.x, d3);
        d3 = fmaf(th.z, bb.y, d3); d3 = fmaf(th.w, bb.z, d3);
        fsum0 += (a.x + a.y) + (a.z + a.w);
        fss0 = fmaf(a.x, a.x, fss0); fss0 = fmaf(a.y, a.y, fss0);
        fss0 = fmaf(a.z, a.z, fss0); fss0 = fmaf(a.w, a.w, fss0);
        a = bb;
    }

    if (h == 1) {
        part_lds[q][0] = d0; part_lds[q][1] = d1;
        part_lds[q][2] = d2; part_lds[q][3] = d3;
        part_lds[q][4] = fsum0; part_lds[q][5] = fss0;
    }
    __syncthreads();
    if (h == 0) {
        d0 += part_lds[q][0]; d1 += part_lds[q][1];
        d2 += part_lds[q][2]; d3 += part_lds[q][3];
        fsum0 += part_lds[q][4]; fss0 += part_lds[q][5];

        const float a00 = f_lds[4*q + 0], a01 = f_lds[4*q + 1], a02 = f_lds[4*q + 2];
        const float b00 = f_lds[4*q + 512], b01 = f_lds[4*q + 513], b02 = f_lds[4*q + 514];
        const float fsum1 = fsum0 - a00 + b00;
        const float fsum2 = fsum1 - a01 + b01;
        const float fsum3 = fsum2 - a02 + b02;
        float fss1 = fss0 - a00 * a00; fss1 = fmaf(b00, b00, fss1);
        float fss2 = fss1 - a01 * a01; fss2 = fmaf(b01, b01, fss2);
        float fss3 = fss2 - a02 * a02; fss3 = fmaf(b02, b02, fss3);

        const float th512 = theta[512];
        const float th513 = theta[513];
        const float sall  = thsum + th512 + th513;
        const float A_    = (512.0f - 1.0f / 514.0f) / 513.0f;
        const float rsqA  = fast_rsq(A_);
        const float cE    = th513 - sall * (1.0f / 514.0f);
        if (b == 0 && tid == 0) cpool[0] = KC * (th512 - sall * (1.0f / 514.0f));  // Gp

        float ez[4], pv[4];
        const float fs_[4] = { fsum0, fsum1, fsum2, fsum3 };
        const float fq_[4] = { fss0,  fss1,  fss2,  fss3  };
        const float dd_[4] = { d0, d1, d2, d3 };
#pragma unroll
        for (int c = 0; c < 4; ++c) {
            float m    = fs_[c] * (1.0f / 512.0f);
            float varw = (fq_[c] - fs_[c] * m) * (1.0f / 511.0f);
            float dn   = (dd_[c] - m * thsum) * fast_rsq(varw);
            ez[c] = KC * (dn + cE);
            pv[c] = fast_rcp(1.0f + fast_exp2(ez[c] * rsqA));
        }

        const int t4i = b * 512 + 4 * q;
        if (t4i + 3 < NSTEPS) {
            ((float4*)e_out)[b * 128 + q]  = make_float4(ez[0], ez[1], ez[2], ez[3]);
            ((float4*)p0_out)[b * 128 + q] = make_float4(pv[0], pv[1], pv[2], pv[3]);
        } else {
#pragma unroll
            for (int c = 0; c < 4; ++c)
                if (t4i + c < NSTEPS) { e_out[t4i + c] = ez[c]; p0_out[t4i + c] = pv[c]; }
        }

        // per-64-step partials: 16 threads cover one 64-chunk
        float c1 = 0.f, c2 = 0.f;
#pragma unroll
        for (int c = 0; c < 4; ++c) {
            float p = (t4i + c < NSTEPS) ? pv[c] : 0.f;
            c1 += p; c2 = fmaf(p, p, c2);
        }
#pragma unroll
        for (int d = 8; d; d >>= 1) {
            c1 += __shfl_down(c1, d, 16);
            c2 += __shfl_down(c2, d, 16);
        }
        if ((q & 15) == 0) {
            int idx = b * 8 + (q >> 4);    // 0..2047
            bs[idx] = c1; bss[idx] = c2;
        }
    }
}

// -------- Phase B: 2048 chunks x (12 warm + 64) p-recurrence --------
// 32 blocks x 64 lanes; preamble loads batched/predicated (no serial-latency loops).
__global__ __launch_bounds__(64, 1) void pos_kernel(
    const float* __restrict__ p_init,
    const float* __restrict__ e,
    const float* __restrict__ p0,
    const float* __restrict__ bs,
    const float* __restrict__ bss,
    const float* __restrict__ cpool,
    float* __restrict__ P)
{
    const int l = threadIdx.x;
    const int b = blockIdx.x;
    const int g = b * 64 + l;            // 0..2047

    // exact p_init sums: 2 predicated float4 + tail scalar per lane, all independent
    float sa, qa;
    {
        const float4* p4 = (const float4*)p_init;
        float4 v0 = p4[l];                                        // elems 0..255
        float4 v1 = (l <= 62) ? p4[64 + l] : make_float4(0.f,0.f,0.f,0.f);  // 256..507
        float  t0 = (l < 3) ? p_init[508 + l] : 0.f;              // 508..510
        sa = ((v0.x + v0.y) + (v0.z + v0.w)) + ((v1.x + v1.y) + (v1.z + v1.w)) + t0;
        qa = fmaf(v0.x, v0.x, v0.y * v0.y) + fmaf(v0.z, v0.z, v0.w * v0.w)
           + fmaf(v1.x, v1.x, v1.y * v1.y) + fmaf(v1.z, v1.z, v1.w * v1.w)
           + t0 * t0;
#pragma unroll
        for (int d = 32; d; d >>= 1) { sa += __shfl_xor(sa, d, 64); qa += __shfl_xor(qa, d, 64); }
    }

    // prefix base over previous blocks: 8 predicated float4 per lane, independent
    float ba = 0.f, ca = 0.f;
    {
        const float4* b4 = (const float4*)bs;
        const float4* c4 = (const float4*)bss;
        const int lim = b * 16;          // float4 count covering bs[0 .. b*64)
#pragma unroll
        for (int k = 0; k < 8; ++k) {
            int idx = l + 64 * k;        // 0..511
            bool v = idx < lim;
            float4 vb4 = v ? b4[idx] : make_float4(0.f,0.f,0.f,0.f);
            float4 vc4 = v ? c4[idx] : make_float4(0.f,0.f,0.f,0.f);
            ba += (vb4.x + vb4.y) + (vb4.z + vb4.w);
            ca += (vc4.x + vc4.y) + (vc4.z + vc4.w);
        }
#pragma unroll
        for (int d = 32; d; d >>= 1) { ba += __shfl_xor(ba, d, 64); ca += __shfl_xor(ca, d, 64); }
    }

    // in-block exclusive scan of this block's 64 partials
    float vb = bs[g], vc = bss[g];
    float ib = vb, ic = vc;
#pragma unroll
    for (int d = 1; d < 64; d <<= 1) {
        float ub = __shfl_up(ib, d, 64);
        float uc = __shfl_up(ic, d, 64);
        if (l >= d) { ib += ub; ic += uc; }
    }
    float s  = sa + ba + (ib - vb);
    float ss = qa + ca + (ic - vc);

    if (g > 2040) return;   // last useful chunk: k0 = 2040*64 = 130560 < NSTEPS

    const float Gp = cpool[0];
    const float A_ = (512.0f - 1.0f / 514.0f) / 513.0f;
    const float B_ = (1.0f - 1.0f / 514.0f) / 513.0f;
    const float C_ = -2.0f / (514.0f * 513.0f);

    const int k0   = g * 64;
    const int kend = (k0 + 64 < NSTEPS) ? k0 + 64 : NSTEPS;
    const int kw   = (g == 0) ? 0 : k0 - 12;

    float plast = (g == 0) ? p_init[510] : p0[k0 - 13];
    float nf    = 511.0f + (float)k0;
    float rnm1  = fast_rcp(nf - 1.0f);
    const float mean_f = s * fast_rcp(nf);
    const float rv_f   = fast_rsq(fmaf(-s, mean_f, ss) * rnm1);

    const float4* e4 = (const float4*)(e + kw);   // kw % 4 == 0
    const int maxi = (NPAD / 4 - 1) - (kw >> 2);

    float4 er[19];
#pragma unroll
    for (int i = 0; i < 19; ++i) er[i] = e4[i < maxi ? i : maxi];

#define BSTEP(EK, I) { \
    float rn   = fast_rcp(nf); \
    float mean = s * rn; \
    float varp = fmaf(-s, mean, ss) * rnm1; \
    float rv   = fast_rsq(varp); \
    float u    = (plast - mean) * rv; \
    float vx   = fmaf(u, fmaf(B_, u, C_), A_); \
    float r2   = fast_rsq(vx); \
    float z    = fmaf(u, Gp, (EK)) * r2; \
    float w    = fast_exp2(z); \
    float pnew = fast_rcp(1.0f + w); \
    s += pnew; ss = fmaf(pnew, pnew, ss); plast = pnew; \
    rnm1 = rn; nf += 1.0f; \
    int k = kw + (I); \
    if (k < kend) P[511 + k] = pnew; }
#define BWARM(EK) { \
    float u  = (plast - mean_f) * rv_f; \
    float vx = fmaf(u, fmaf(B_, u, C_), A_); \
    float r2 = fast_rsq(vx); \
    float z  = fmaf(u, Gp, (EK)) * r2; \
    plast = fast_rcp(1.0f + fast_exp2(z)); }
#define B4(Q, IB) { BSTEP(Q.x, IB+0); BSTEP(Q.y, IB+1); BSTEP(Q.z, IB+2); BSTEP(Q.w, IB+3); }
#define W4(Q) { BWARM(Q.x); BWARM(Q.y); BWARM(Q.z); BWARM(Q.w); }

    if (g == 0) { B4(er[0], 0); B4(er[1], 4); B4(er[2], 8); }
    else        { W4(er[0]);    W4(er[1]);    W4(er[2]);    }
    B4(er[3], 12);  B4(er[4], 16);  B4(er[5], 20);  B4(er[6], 24);
    B4(er[7], 28);  B4(er[8], 32);  B4(er[9], 36);  B4(er[10],40);
    B4(er[11],44);  B4(er[12],48);  B4(er[13],52);  B4(er[14],56);
    B4(er[15],60);  B4(er[16],64);  B4(er[17],68);  B4(er[18],72);
#undef BSTEP
#undef BWARM
#undef B4
#undef W4
}

// -------- Phase C: 4096 chunks x (8 warm + 32) portfolio --------
__global__ __launch_bounds__(64, 1) void port_kernel(
    const float* __restrict__ ar,
    const float* __restrict__ Pp,
    float* __restrict__ out)
{
    const int g = blockIdx.x * 64 + threadIdx.x;   // 0..4095
    const int t0   = g * 32;
    const int t0w  = (g == 0) ? 1 : t0;
    const int tend = (t0 + 32 < T_TOTAL) ? t0 + 32 : T_TOTAL;
    const int tw   = (g == 0) ? 0 : t0 - 8;

    float x = Pp[(g == 0) ? 0 : (tw - 1)];
    float inv = x, cash = 1.0f - x, pvprev = 1.0f;
    if (g == 0) out[0] = 1.0f;

    const float4* P4 = (const float4*)(Pp + tw);   // tw % 4 == 0
    const float4* A4 = (const float4*)(ar + tw);

    float4 pr[10], arr[10];
#pragma unroll
    for (int i = 0; i < 10; ++i) { pr[i] = P4[i]; arr[i] = A4[i]; }

#define CST(RR, PPV, I) { \
    int t = tw + (I); \
    if (t >= 1) { \
        float invn  = inv * (RR); \
        float pv    = invn + cash; \
        float delta = fmaf(pv, (PPV), -invn); \
        float dfee  = delta * OMF; \
        bool  pos   = delta > 0.0f; \
        inv  = invn + (pos ? dfee : delta); \
        cash = cash - (pos ? delta : dfee); \
        float pvn = inv + cash; \
        if (t >= t0w && t < tend) out[t] = pvn * fast_rcp(pvprev); \
        pvprev = pvn; } }
#define C4(PQ, AQ, IB) { CST(AQ.x, PQ.x, IB+0); CST(AQ.y, PQ.y, IB+1); \
                         CST(AQ.z, PQ.z, IB+2); CST(AQ.w, PQ.w, IB+3); }

    C4(pr[0], arr[0], 0);   C4(pr[1], arr[1], 4);
    C4(pr[2], arr[2], 8);   C4(pr[3], arr[3], 12);
    C4(pr[4], arr[4], 16);  C4(pr[5], arr[5], 20);
    C4(pr[6], arr[6], 24);  C4(pr[7], arr[7], 28);
    C4(pr[8], arr[8], 32);  C4(pr[9], arr[9], 36);
#undef CST
#undef C4
}

extern "C" void kernel_launch(void* const* d_in, const int* in_sizes, int n_in,
                              void* d_out, int out_size, void* d_ws, size_t ws_size,
                              hipStream_t stream) {
    const float* features      = (const float*)d_in[0];
    const float* asset_returns = (const float*)d_in[1];
    const float* theta         = (const float*)d_in[2];
    const float* p_init        = (const float*)d_in[3];
    float* out = (float*)d_out;
    float* ws  = (float*)d_ws;

    float* e_arr = ws + OFF_E;
    float* p0    = ws + OFF_P0;
    float* P     = ws + OFF_P;
    float* bs    = ws + OFF_BS;
    float* bss   = ws + OFF_BSS;
    float* cpool = ws + OFF_CP;

    precompute_kernel<<<256, 256, 0, stream>>>(features, theta, p_init,
                                               e_arr, p0, P, bs, bss, cpool);
    pos_kernel<<<32, 64, 0, stream>>>(p_init, e_arr, p0, bs, bss, cpool, P);
    port_kernel<<<64, 64, 0, stream>>>(asset_returns, P, out);
}

// Round 7
// 83.372 us; speedup vs baseline: 1.5883x; 1.0168x over previous
//
#include <hip/hip_runtime.h>
#include <math.h>

// Problem constants
#define T_TOTAL 131072
#define LB      512
#define NSTEPS  130561          // T - LB + 1
#define NPAD    130564          // NSTEPS rounded up to multiple of 4
#define OMF     0.99975f        // 1 - FEES
#define KC     -1.4426950408889634f   // -log2(e)

// ws layout (float offsets)
#define OFF_E    0
#define OFF_P0   (NPAD)
#define OFF_P    (2*NPAD)
#define OFF_BS   (2*NPAD + T_TOTAL)
#define OFF_BSS  (OFF_BS + 2048)
#define OFF_CP   (OFF_BSS + 2048)

static __device__ __forceinline__ float fast_rcp(float x) {
#if __has_builtin(__builtin_amdgcn_rcpf)
    return __builtin_amdgcn_rcpf(x);
#else
    return 1.0f / x;
#endif
}
static __device__ __forceinline__ float fast_rsq(float x) {
#if __has_builtin(__builtin_amdgcn_rsqf)
    return __builtin_amdgcn_rsqf(x);
#else
    return 1.0f / sqrtf(x);
#endif
}
static __device__ __forceinline__ float fast_exp2(float x) {
#if __has_builtin(__builtin_amdgcn_exp2f)
    return __builtin_amdgcn_exp2f(x);
#else
    return exp2f(x);
#endif
}

// -------- Phase A: split-K x4 FIR precompute --------
// 512 blocks x 256 threads (2 blocks/CU -> 2 waves/SIMD for latency hiding).
// Block covers 256 outputs: q = tid&63 owns an output quad, h = tid>>6 does
// taps [128h, 128h+128). Quarters combined via stride-9-padded LDS.
// Emits e[t], p0[t], per-64-chunk partials bs/bss (2048), P[0..510], Gp.
__global__ __launch_bounds__(256, 2) void precompute_kernel(
    const float* __restrict__ features,
    const float* __restrict__ theta,
    const float* __restrict__ p_init,
    float* __restrict__ e_out,
    float* __restrict__ p0_out,
    float* __restrict__ P,
    float* __restrict__ bs,
    float* __restrict__ bss,
    float* __restrict__ cpool)
{
    __shared__ float f_lds[776];           // 194 float4: 256 outputs + 512 window + pad
    __shared__ float th_lds[512];          // 128 float4
    __shared__ float part_lds[3][64][9];   // stride 9: gcd(9,32)=1 -> conflict-free
    const int tid = threadIdx.x;
    const int b   = blockIdx.x;            // 0..511
    const int q   = tid & 63;              // output-quad index in block
    const int h   = tid >> 6;              // tap quarter (0..3)

    {
        const float4* fg = (const float4*)features;
        float4* f4s = (float4*)f_lds;
        if (tid < 194) {
            int g0 = b * 64 + tid; g0 = g0 > 32767 ? 32767 : g0;
            f4s[tid] = fg[g0];
        }
        if (tid < 128) ((float4*)th_lds)[tid] = ((const float4*)theta)[tid];
    }
    if (b == 0) {
        P[tid] = p_init[tid < 511 ? tid : 510];
        if (tid + 256 < 511) P[tid + 256] = p_init[tid + 256];
    }
    __syncthreads();

    // wave-uniform thsum
    float thsum = 0.f;
    {
        int l6 = tid & 63;
#pragma unroll
        for (int j = 0; j < 8; ++j) thsum += th_lds[l6 + 64 * j];
#pragma unroll
        for (int d = 32; d; d >>= 1) thsum += __shfl_xor(thsum, d, 64);
    }

    const float4* f4 = (const float4*)f_lds;
    const float4* t4 = (const float4*)th_lds;

    float d0 = 0.f, d1 = 0.f, d2 = 0.f, d3 = 0.f;
    float fsum0 = 0.f, fss0 = 0.f;
    const int jt0 = 32 * h;
    float4 a = f4[q + jt0];
#pragma unroll 4
    for (int j = 0; j < 32; ++j) {
        float4 bb = f4[q + jt0 + j + 1];
        float4 th = t4[jt0 + j];
        d0 = fmaf(th.x, a.x, d0); d0 = fmaf(th.y, a.y, d0);
        d0 = fmaf(th.z, a.z, d0); d0 = fmaf(th.w, a.w, d0);
        d1 = fmaf(th.x, a.y, d1); d1 = fmaf(th.y, a.z, d1);
        d1 = fmaf(th.z, a.w, d1); d1 = fmaf(th.w, bb.x, d1);
        d2 = fmaf(th.x, a.z, d2); d2 = fmaf(th.y, a.w, d2);
        d2 = fmaf(th.z, bb.x, d2); d2 = fmaf(th.w, bb.y, d2);
        d3 = fmaf(th.x, a.w, d3); d3 = fmaf(th.y, bb.x, d3);
        d3 = fmaf(th.z, bb.y, d3); d3 = fmaf(th.w, bb.z, d3);
        fsum0 += (a.x + a.y) + (a.z + a.w);
        fss0 = fmaf(a.x, a.x, fss0); fss0 = fmaf(a.y, a.y, fss0);
        fss0 = fmaf(a.z, a.z, fss0); fss0 = fmaf(a.w, a.w, fss0);
        a = bb;
    }

    if (h != 0) {
        part_lds[h - 1][q][0] = d0; part_lds[h - 1][q][1] = d1;
        part_lds[h - 1][q][2] = d2; part_lds[h - 1][q][3] = d3;
        part_lds[h - 1][q][4] = fsum0; part_lds[h - 1][q][5] = fss0;
    }
    __syncthreads();
    if (h == 0) {
#pragma unroll
        for (int r = 0; r < 3; ++r) {
            d0 += part_lds[r][q][0]; d1 += part_lds[r][q][1];
            d2 += part_lds[r][q][2]; d3 += part_lds[r][q][3];
            fsum0 += part_lds[r][q][4]; fss0 += part_lds[r][q][5];
        }

        const float a00 = f_lds[4*q + 0], a01 = f_lds[4*q + 1], a02 = f_lds[4*q + 2];
        const float b00 = f_lds[4*q + 512], b01 = f_lds[4*q + 513], b02 = f_lds[4*q + 514];
        const float fsum1 = fsum0 - a00 + b00;
        const float fsum2 = fsum1 - a01 + b01;
        const float fsum3 = fsum2 - a02 + b02;
        float fss1 = fss0 - a00 * a00; fss1 = fmaf(b00, b00, fss1);
        float fss2 = fss1 - a01 * a01; fss2 = fmaf(b01, b01, fss2);
        float fss3 = fss2 - a02 * a02; fss3 = fmaf(b02, b02, fss3);

        const float th512 = theta[512];
        const float th513 = theta[513];
        const float sall  = thsum + th512 + th513;
        const float A_    = (512.0f - 1.0f / 514.0f) / 513.0f;
        const float rsqA  = fast_rsq(A_);
        const float cE    = th513 - sall * (1.0f / 514.0f);
        if (b == 0 && tid == 0) cpool[0] = KC * (th512 - sall * (1.0f / 514.0f));  // Gp

        float ez[4], pv[4];
        const float fs_[4] = { fsum0, fsum1, fsum2, fsum3 };
        const float fq_[4] = { fss0,  fss1,  fss2,  fss3  };
        const float dd_[4] = { d0, d1, d2, d3 };
#pragma unroll
        for (int c = 0; c < 4; ++c) {
            float m    = fs_[c] * (1.0f / 512.0f);
            float varw = (fq_[c] - fs_[c] * m) * (1.0f / 511.0f);
            float dn   = (dd_[c] - m * thsum) * fast_rsq(varw);
            ez[c] = KC * (dn + cE);
            pv[c] = fast_rcp(1.0f + fast_exp2(ez[c] * rsqA));
        }

        const int t4i = b * 256 + 4 * q;
        if (t4i + 3 < NSTEPS) {
            ((float4*)e_out)[b * 64 + q]  = make_float4(ez[0], ez[1], ez[2], ez[3]);
            ((float4*)p0_out)[b * 64 + q] = make_float4(pv[0], pv[1], pv[2], pv[3]);
        } else {
#pragma unroll
            for (int c = 0; c < 4; ++c)
                if (t4i + c < NSTEPS) { e_out[t4i + c] = ez[c]; p0_out[t4i + c] = pv[c]; }
        }

        // per-64-step partials: 16 lanes cover one 64-chunk
        float c1 = 0.f, c2 = 0.f;
#pragma unroll
        for (int c = 0; c < 4; ++c) {
            float p = (t4i + c < NSTEPS) ? pv[c] : 0.f;
            c1 += p; c2 = fmaf(p, p, c2);
        }
#pragma unroll
        for (int d = 8; d; d >>= 1) {
            c1 += __shfl_down(c1, d, 16);
            c2 += __shfl_down(c2, d, 16);
        }
        if ((q & 15) == 0) {
            int idx = b * 4 + (q >> 4);    // 0..2047
            bs[idx] = c1; bss[idx] = c2;
        }
    }
}

// -------- Phase B: 2048 chunks x (12 warm + 64) p-recurrence --------
// 32 blocks x 64 lanes; preamble loads batched/predicated (no serial-latency loops).
__global__ __launch_bounds__(64, 1) void pos_kernel(
    const float* __restrict__ p_init,
    const float* __restrict__ e,
    const float* __restrict__ p0,
    const float* __restrict__ bs,
    const float* __restrict__ bss,
    const float* __restrict__ cpool,
    float* __restrict__ P)
{
    const int l = threadIdx.x;
    const int b = blockIdx.x;
    const int g = b * 64 + l;            // 0..2047

    // exact p_init sums: 2 predicated float4 + tail scalar per lane, all independent
    float sa, qa;
    {
        const float4* p4 = (const float4*)p_init;
        float4 v0 = p4[l];                                        // elems 0..255
        float4 v1 = (l <= 62) ? p4[64 + l] : make_float4(0.f,0.f,0.f,0.f);  // 256..507
        float  t0 = (l < 3) ? p_init[508 + l] : 0.f;              // 508..510
        sa = ((v0.x + v0.y) + (v0.z + v0.w)) + ((v1.x + v1.y) + (v1.z + v1.w)) + t0;
        qa = fmaf(v0.x, v0.x, v0.y * v0.y) + fmaf(v0.z, v0.z, v0.w * v0.w)
           + fmaf(v1.x, v1.x, v1.y * v1.y) + fmaf(v1.z, v1.z, v1.w * v1.w)
           + t0 * t0;
#pragma unroll
        for (int d = 32; d; d >>= 1) { sa += __shfl_xor(sa, d, 64); qa += __shfl_xor(qa, d, 64); }
    }

    // prefix base over previous blocks: 8 predicated float4 per lane, independent
    float ba = 0.f, ca = 0.f;
    {
        const float4* b4 = (const float4*)bs;
        const float4* c4 = (const float4*)bss;
        const int lim = b * 16;          // float4 count covering bs[0 .. b*64)
#pragma unroll
        for (int k = 0; k < 8; ++k) {
            int idx = l + 64 * k;        // 0..511
            bool v = idx < lim;
            float4 vb4 = v ? b4[idx] : make_float4(0.f,0.f,0.f,0.f);
            float4 vc4 = v ? c4[idx] : make_float4(0.f,0.f,0.f,0.f);
            ba += (vb4.x + vb4.y) + (vb4.z + vb4.w);
            ca += (vc4.x + vc4.y) + (vc4.z + vc4.w);
        }
#pragma unroll
        for (int d = 32; d; d >>= 1) { ba += __shfl_xor(ba, d, 64); ca += __shfl_xor(ca, d, 64); }
    }

    // in-block exclusive scan of this block's 64 partials
    float vb = bs[g], vc = bss[g];
    float ib = vb, ic = vc;
#pragma unroll
    for (int d = 1; d < 64; d <<= 1) {
        float ub = __shfl_up(ib, d, 64);
        float uc = __shfl_up(ic, d, 64);
        if (l >= d) { ib += ub; ic += uc; }
    }
    float s  = sa + ba + (ib - vb);
    float ss = qa + ca + (ic - vc);

    if (g > 2040) return;   // last useful chunk: k0 = 2040*64 = 130560 < NSTEPS

    const float Gp = cpool[0];
    const float A_ = (512.0f - 1.0f / 514.0f) / 513.0f;
    const float B_ = (1.0f - 1.0f / 514.0f) / 513.0f;
    const float C_ = -2.0f / (514.0f * 513.0f);

    const int k0   = g * 64;
    const int kend = (k0 + 64 < NSTEPS) ? k0 + 64 : NSTEPS;
    const int kw   = (g == 0) ? 0 : k0 - 12;

    float plast = (g == 0) ? p_init[510] : p0[k0 - 13];
    float nf    = 511.0f + (float)k0;
    float rnm1  = fast_rcp(nf - 1.0f);
    const float mean_f = s * fast_rcp(nf);
    const float rv_f   = fast_rsq(fmaf(-s, mean_f, ss) * rnm1);

    const float4* e4 = (const float4*)(e + kw);   // kw % 4 == 0
    const int maxi = (NPAD / 4 - 1) - (kw >> 2);

    float4 er[19];
#pragma unroll
    for (int i = 0; i < 19; ++i) er[i] = e4[i < maxi ? i : maxi];

#define BSTEP(EK, I) { \
    float rn   = fast_rcp(nf); \
    float mean = s * rn; \
    float varp = fmaf(-s, mean, ss) * rnm1; \
    float rv   = fast_rsq(varp); \
    float u    = (plast - mean) * rv; \
    float vx   = fmaf(u, fmaf(B_, u, C_), A_); \
    float r2   = fast_rsq(vx); \
    float z    = fmaf(u, Gp, (EK)) * r2; \
    float w    = fast_exp2(z); \
    float pnew = fast_rcp(1.0f + w); \
    s += pnew; ss = fmaf(pnew, pnew, ss); plast = pnew; \
    rnm1 = rn; nf += 1.0f; \
    int k = kw + (I); \
    if (k < kend) P[511 + k] = pnew; }
#define BWARM(EK) { \
    float u  = (plast - mean_f) * rv_f; \
    float vx = fmaf(u, fmaf(B_, u, C_), A_); \
    float r2 = fast_rsq(vx); \
    float z  = fmaf(u, Gp, (EK)) * r2; \
    plast = fast_rcp(1.0f + fast_exp2(z)); }
#define B4(Q, IB) { BSTEP(Q.x, IB+0); BSTEP(Q.y, IB+1); BSTEP(Q.z, IB+2); BSTEP(Q.w, IB+3); }
#define W4(Q) { BWARM(Q.x); BWARM(Q.y); BWARM(Q.z); BWARM(Q.w); }

    if (g == 0) { B4(er[0], 0); B4(er[1], 4); B4(er[2], 8); }
    else        { W4(er[0]);    W4(er[1]);    W4(er[2]);    }
    B4(er[3], 12);  B4(er[4], 16);  B4(er[5], 20);  B4(er[6], 24);
    B4(er[7], 28);  B4(er[8], 32);  B4(er[9], 36);  B4(er[10],40);
    B4(er[11],44);  B4(er[12],48);  B4(er[13],52);  B4(er[14],56);
    B4(er[15],60);  B4(er[16],64);  B4(er[17],68);  B4(er[18],72);
#undef BSTEP
#undef BWARM
#undef B4
#undef W4
}

// -------- Phase C: 4096 chunks x (8 warm + 32) portfolio --------
__global__ __launch_bounds__(64, 1) void port_kernel(
    const float* __restrict__ ar,
    const float* __restrict__ Pp,
    float* __restrict__ out)
{
    const int g = blockIdx.x * 64 + threadIdx.x;   // 0..4095
    const int t0   = g * 32;
    const int t0w  = (g == 0) ? 1 : t0;
    const int tend = (t0 + 32 < T_TOTAL) ? t0 + 32 : T_TOTAL;
    const int tw   = (g == 0) ? 0 : t0 - 8;

    float x = Pp[(g == 0) ? 0 : (tw - 1)];
    float inv = x, cash = 1.0f - x, pvprev = 1.0f;
    if (g == 0) out[0] = 1.0f;

    const float4* P4 = (const float4*)(Pp + tw);   // tw % 4 == 0
    const float4* A4 = (const float4*)(ar + tw);

    float4 pr[10], arr[10];
#pragma unroll
    for (int i = 0; i < 10; ++i) { pr[i] = P4[i]; arr[i] = A4[i]; }

#define CST(RR, PPV, I) { \
    int t = tw + (I); \
    if (t >= 1) { \
        float invn  = inv * (RR); \
        float pv    = invn + cash; \
        float delta = fmaf(pv, (PPV), -invn); \
        float dfee  = delta * OMF; \
        bool  pos   = delta > 0.0f; \
        inv  = invn + (pos ? dfee : delta); \
        cash = cash - (pos ? delta : dfee); \
        float pvn = inv + cash; \
        if (t >= t0w && t < tend) out[t] = pvn * fast_rcp(pvprev); \
        pvprev = pvn; } }
#define C4(PQ, AQ, IB) { CST(AQ.x, PQ.x, IB+0); CST(AQ.y, PQ.y, IB+1); \
                         CST(AQ.z, PQ.z, IB+2); CST(AQ.w, PQ.w, IB+3); }

    C4(pr[0], arr[0], 0);   C4(pr[1], arr[1], 4);
    C4(pr[2], arr[2], 8);   C4(pr[3], arr[3], 12);
    C4(pr[4], arr[4], 16);  C4(pr[5], arr[5], 20);
    C4(pr[6], arr[6], 24);  C4(pr[7], arr[7], 28);
    C4(pr[8], arr[8], 32);  C4(pr[9], arr[9], 36);
#undef CST
#undef C4
}

extern "C" void kernel_launch(void* const* d_in, const int* in_sizes, int n_in,
                              void* d_out, int out_size, void* d_ws, size_t ws_size,
                              hipStream_t stream) {
    const float* features      = (const float*)d_in[0];
    const float* asset_returns = (const float*)d_in[1];
    const float* theta         = (const float*)d_in[2];
    const float* p_init        = (const float*)d_in[3];
    float* out = (float*)d_out;
    float* ws  = (float*)d_ws;

    float* e_arr = ws + OFF_E;
    float* p0    = ws + OFF_P0;
    float* P     = ws + OFF_P;
    float* bs    = ws + OFF_BS;
    float* bss   = ws + OFF_BSS;
    float* cpool = ws + OFF_CP;

    precompute_kernel<<<512, 256, 0, stream>>>(features, theta, p_init,
                                               e_arr, p0, P, bs, bss, cpool);
    pos_kernel<<<32, 64, 0, stream>>>(p_init, e_arr, p0, bs, bss, cpool, P);
    port_kernel<<<64, 64, 0, stream>>>(asset_returns, P, out);
}